// Round 5
// baseline (200.440 us; speedup 1.0000x reference)
//
#include <hip/hip_runtime.h>
#include <math.h>

// X[8192,64], Y[8192,64] fp32.
// d2[i][j] = x2_i + y2_j - 2<x_i,y_j>;  out = mean_i sqrt(min_j d2) + mean_j sqrt(min_i d2)
//
// R10: ONE ordinary launch (512 blocks x 256 = 2 blocks/CU, all co-resident),
// phases separated by hand-rolled device-scope atomic spin barriers (R8's
// cooperative launch never executed under harness graph capture; hand-rolled
// barriers need no special launch API). Counters live in d_ws and rely on the
// documented per-iteration 0xAA poison fill: init value 0xAAAAAAAA, target
// 0xAAAAAAAA+512 -> re-armed every iteration by the fill itself.
// Phase 0: prep (fp32->bf16, X pre-scaled by -2: exact; row squares).
// Phase 1: mine — byte-identical to R7's verified kernel (A register-
// persistent, B LDS double-buffered, one barrier/chunk, 16x16x32 bf16 MFMA,
// C init = x2_i + y2_j so acc exits as d2, pure v_min3_f32 epilogue, row-half
// col partials combined via LDS -> cslab [64][8192]).
// Phase 2: finish on blocks 0..159 (blocks >=160 release and exit).
// Harness d_ws 0xAA fill (~41us, 268MB) is inside the timed window and is a
// fixed floor we cannot affect.

#define NROWS 8192
#define DDIM  64
#define ITILES 64     // 8192 / 128 i-rows per block
#define SLICES 8      // j: 8 slices x 1024
#define CHUNKS 8      // 8 x 128 j per block
#define LSTR 72       // LDS row stride (bf16): 144 B -> 16B-aligned, 2-way-max banks
#define NBLOCKS (ITILES * SLICES)              // 512
#define CTR_TARGET (0xAAAAAAAAu + (unsigned)NBLOCKS)

typedef __bf16 bf16_t;
typedef bf16_t bf16x8 __attribute__((ext_vector_type(8)));
typedef float  f32x4  __attribute__((ext_vector_type(4)));

__global__ __launch_bounds__(256, 2)
void fused_kernel(const float* __restrict__ X, const float* __restrict__ Y,
                  bf16_t* __restrict__ Xbf, bf16_t* __restrict__ Ybf,
                  float* __restrict__ x2g, float* __restrict__ y2g,
                  float* __restrict__ rslab, float* __restrict__ cslab,
                  unsigned* __restrict__ c0, unsigned* __restrict__ c1,
                  float* __restrict__ out) {
  __shared__ bf16_t Ys[2][128 * LSTR];   // 2 x 18 KB
  __shared__ float credL[2][2][128];     // [parity][rh][col] col-partial exchange

  const int tid = threadIdx.x;

  // ================= phase 0: prep (131072 threads, 8 per row) =================
  {
    int t = blockIdx.x * 256 + tid;                // 0..131071
    int r16 = t >> 3;                              // 0..16383
    int half = r16 >> 13;                          // 0: X, 1: Y
    int r = r16 & (NROWS - 1);
    int part = t & 7;                              // 8 elems per thread
    const float* src = half ? Y : X;
    bf16_t* dst = half ? Ybf : Xbf;
    float* sq = half ? y2g : x2g;
    // X rows pre-scaled by -2 so the MFMA computes -2<x,y> directly.
    // Scaling by 2 is an exponent shift: bf16(-2x) == -2*bf16(x) exactly.
    const float scale = half ? 1.0f : -2.0f;

    const float4* p = (const float4*)(src + r * DDIM + part * 8);
    float4 v0 = p[0], v1 = p[1];
    float s = 0.f;
    s = fmaf(v0.x, v0.x, s); s = fmaf(v0.y, v0.y, s);
    s = fmaf(v0.z, v0.z, s); s = fmaf(v0.w, v0.w, s);
    s = fmaf(v1.x, v1.x, s); s = fmaf(v1.y, v1.y, s);
    s = fmaf(v1.z, v1.z, s); s = fmaf(v1.w, v1.w, s);

    bf16x8 h = {(bf16_t)(scale * v0.x), (bf16_t)(scale * v0.y),
                (bf16_t)(scale * v0.z), (bf16_t)(scale * v0.w),
                (bf16_t)(scale * v1.x), (bf16_t)(scale * v1.y),
                (bf16_t)(scale * v1.z), (bf16_t)(scale * v1.w)};
    *(bf16x8*)&dst[r * DDIM + part * 8] = h;

    s += __shfl_xor(s, 1, 64);
    s += __shfl_xor(s, 2, 64);
    s += __shfl_xor(s, 4, 64);
    if (part == 0) sq[r] = s;
    if (t == 0) out[0] = 0.f;
  }

  // ---- barrier 1: all prep stores visible device-wide before mine ----
  __threadfence();
  __syncthreads();
  if (tid == 0) {
    __hip_atomic_fetch_add(c0, 1u, __ATOMIC_ACQ_REL, __HIP_MEMORY_SCOPE_AGENT);
    while (__hip_atomic_load(c0, __ATOMIC_ACQUIRE, __HIP_MEMORY_SCOPE_AGENT)
           != CTR_TARGET)
      __builtin_amdgcn_s_sleep(8);
  }
  __syncthreads();

  // ================= phase 1: mine (byte-identical to R7) =================
  {
    const int L = tid & 63;
    const int w = tid >> 6;
    const int lr = L & 15;
    const int q = L >> 4;
    const int rh = w >> 1;              // wave row-half
    const int ch = w & 1;               // wave col-half
    const int itile = blockIdx.x & (ITILES - 1);
    const int slice = blockIdx.x >> 6;  // 0..7
    const int i0 = itile * 128;
    const int rgb = rh * 64;
    const int cgb = ch * 64;
    const int jbase = slice * (CHUNKS * 128);   // slice * 1024

    // ---- A fragments: register-persistent (Xbf holds -2*X) ----
    bf16x8 Af[8];
#pragma unroll
    for (int a = 0; a < 4; ++a) {
      int row = i0 + rgb + a * 16 + lr;
#pragma unroll
      for (int h = 0; h < 2; ++h)
        Af[a * 2 + h] = *(const bf16x8*)&Xbf[row * DDIM + h * 32 + q * 8];
    }
    float x2r[16];
#pragma unroll
    for (int a = 0; a < 4; ++a) {
      float4 v = *(const float4*)&x2g[i0 + rgb + a * 16 + q * 4];
      x2r[a * 4 + 0] = v.x; x2r[a * 4 + 1] = v.y;
      x2r[a * 4 + 2] = v.z; x2r[a * 4 + 3] = v.w;
    }

    float rmin[16];
#pragma unroll
    for (int k = 0; k < 16; ++k) rmin[k] = INFINITY;

    // ---- prologue: stage chunk 0 ----
    bf16x8 Bst[4];
#pragma unroll
    for (int p = 0; p < 4; ++p) {
      int f = p * 256 + tid;
      Bst[p] = *(const bf16x8*)&Ybf[(jbase + (f >> 3)) * DDIM + (f & 7) * 8];
    }
#pragma unroll
    for (int p = 0; p < 4; ++p) {
      int f = p * 256 + tid;
      *(bf16x8*)&Ys[0][(f >> 3) * LSTR + (f & 7) * 8] = Bst[p];
    }
    __syncthreads();

    for (int cc = 0; cc < CHUNKS; ++cc) {
      const bf16_t* Yb = Ys[cc & 1];

      // y2 for this chunk (L2-hot, issued early so latency hides under staging)
      float y2c[4];
#pragma unroll
      for (int b = 0; b < 4; ++b)
        y2c[b] = y2g[jbase + cc * 128 + cgb + b * 16 + lr];

      // issue next chunk's global loads now; latency hidden by compute
      if (cc + 1 < CHUNKS) {
        int j0n = jbase + (cc + 1) * 128;
#pragma unroll
        for (int p = 0; p < 4; ++p) {
          int f = p * 256 + tid;
          Bst[p] = *(const bf16x8*)&Ybf[(j0n + (f >> 3)) * DDIM + (f & 7) * 8];
        }
      }

      // C init = x2_i + y2_j  (accumulator exits the MFMA pair as
      // d2 = x2 + y2 - 2<x,y> since A is pre-scaled by -2).
      // C/D layout: col = lr within 16, row = q*4+p.
      f32x4 acc[4][4];
#pragma unroll
      for (int a = 0; a < 4; ++a)
#pragma unroll
        for (int b = 0; b < 4; ++b) {
          acc[a][b][0] = x2r[a * 4 + 0] + y2c[b];
          acc[a][b][1] = x2r[a * 4 + 1] + y2c[b];
          acc[a][b][2] = x2r[a * 4 + 2] + y2c[b];
          acc[a][b][3] = x2r[a * 4 + 3] + y2c[b];
        }

#pragma unroll
      for (int b = 0; b < 4; ++b) {
        bf16x8 B0 = *(const bf16x8*)&Yb[(cgb + b * 16 + lr) * LSTR + q * 8];
        bf16x8 B1 = *(const bf16x8*)&Yb[(cgb + b * 16 + lr) * LSTR + 32 + q * 8];
#pragma unroll
        for (int a = 0; a < 4; ++a) {
          acc[a][b] = __builtin_amdgcn_mfma_f32_16x16x32_bf16(Af[a * 2 + 0], B0, acc[a][b], 0, 0, 0);
          acc[a][b] = __builtin_amdgcn_mfma_f32_16x16x32_bf16(Af[a * 2 + 1], B1, acc[a][b], 0, 0, 0);
        }
      }

      // ---- epilogue: acc IS d2; pure min3 trees ----
      float cmin[4] = {INFINITY, INFINITY, INFINITY, INFINITY};
#pragma unroll
      for (int a = 0; a < 4; ++a) {
#pragma unroll
        for (int p = 0; p < 4; ++p) {
          float rm = rmin[a * 4 + p];
          rm = fminf(fminf(rm, acc[a][0][p]), acc[a][1][p]);
          rmin[a * 4 + p] = fminf(fminf(rm, acc[a][2][p]), acc[a][3][p]);
        }
#pragma unroll
        for (int b = 0; b < 4; ++b) {
          float cm = cmin[b];
          cm = fminf(fminf(cm, acc[a][b][0]), acc[a][b][1]);
          cmin[b] = fminf(fminf(cm, acc[a][b][2]), acc[a][b][3]);
        }
      }
#pragma unroll
      for (int b = 0; b < 4; ++b) {
        cmin[b] = fminf(cmin[b], __shfl_xor(cmin[b], 16, 64));
        cmin[b] = fminf(cmin[b], __shfl_xor(cmin[b], 32, 64));
      }
      float v = cmin[0];
      if (q == 1) v = cmin[1];
      else if (q == 2) v = cmin[2];
      else if (q == 3) v = cmin[3];
      credL[cc & 1][rh][cgb + L] = v;   // col partial (full d2) for this row-half

      // ---- write prefetched chunk into the other buffer, single barrier ----
      if (cc + 1 < CHUNKS) {
        bf16_t* Yn = Ys[(cc + 1) & 1];
#pragma unroll
        for (int p = 0; p < 4; ++p) {
          int f = p * 256 + tid;
          *(bf16x8*)&Yn[(f >> 3) * LSTR + (f & 7) * 8] = Bst[p];
        }
      }
      __syncthreads();

      // combine the two row-halves' col partials; each cslab slot written once.
      // credL[cc&1] is not rewritten until chunk cc+2's epilogue, which is
      // separated from this read by the barrier at the end of chunk cc+1.
      if (tid < 128) {
        float m = fminf(credL[cc & 1][0][tid], credL[cc & 1][1][tid]);
        cslab[itile * NROWS + jbase + cc * 128 + tid] = m;
      }
    }

    // ---- row mins (full d2): reduce across 16 col-lanes, [slice][row][ch] ----
#pragma unroll
    for (int a = 0; a < 4; ++a)
#pragma unroll
      for (int p = 0; p < 4; ++p) {
        float v = rmin[a * 4 + p];
        v = fminf(v, __shfl_xor(v, 1, 64));
        v = fminf(v, __shfl_xor(v, 2, 64));
        v = fminf(v, __shfl_xor(v, 4, 64));
        v = fminf(v, __shfl_xor(v, 8, 64));
        if (lr == 0)
          rslab[slice * (NROWS * 2) + (i0 + rgb + a * 16 + q * 4 + p) * 2 + ch] = v;
      }
  }

  // ---- barrier 2: slab stores visible device-wide; blocks >=160 exit ----
  __threadfence();
  __syncthreads();
  if (blockIdx.x >= 160) {
    if (tid == 0)
      __hip_atomic_fetch_add(c1, 1u, __ATOMIC_ACQ_REL, __HIP_MEMORY_SCOPE_AGENT);
    return;
  }
  if (tid == 0) {
    __hip_atomic_fetch_add(c1, 1u, __ATOMIC_ACQ_REL, __HIP_MEMORY_SCOPE_AGENT);
    while (__hip_atomic_load(c1, __ATOMIC_ACQUIRE, __HIP_MEMORY_SCOPE_AGENT)
           != CTR_TARGET)
      __builtin_amdgcn_s_sleep(8);
  }
  __syncthreads();

  // ================= phase 2: finish (blocks 0..159) =================
  {
    const int b = blockIdx.x;
    if (b < 32) {
      // rows: 256 rows per block
      int row = b * 256 + tid;
      float m = INFINITY;
#pragma unroll
      for (int g = 0; g < SLICES; ++g) {
        float2 v = *(const float2*)&rslab[g * (NROWS * 2) + row * 2];
        m = fminf(m, fminf(v.x, v.y));
      }
      float v = sqrtf(fmaxf(m, 0.f)) * (1.0f / 8192.0f);
#pragma unroll
      for (int off = 32; off > 0; off >>= 1) v += __shfl_down(v, off, 64);
      __shared__ float partial[4];
      if ((tid & 63) == 0) partial[tid >> 6] = v;
      __syncthreads();
      if (tid == 0)
        atomicAdd(out, partial[0] + partial[1] + partial[2] + partial[3]);
    } else {
      // cols: 64 cols per block, 4 thread-segments x 16 partials, LDS combine
      int j = (b - 32) * 64 + (tid & 63);
      int seg = tid >> 6;
      float m = INFINITY;
#pragma unroll
      for (int k = 0; k < 16; ++k)
        m = fminf(m, cslab[(seg * 16 + k) * NROWS + j]);
      __shared__ float red[4][64];
      red[seg][tid & 63] = m;
      __syncthreads();
      if (tid < 64) {
        float mc = fminf(fminf(red[0][tid], red[1][tid]),
                         fminf(red[2][tid], red[3][tid]));
        float v = sqrtf(fmaxf(mc, 0.f)) * (1.0f / 8192.0f);
#pragma unroll
        for (int off = 32; off > 0; off >>= 1) v += __shfl_down(v, off, 64);
        if (tid == 0) atomicAdd(out, v);
      }
    }
  }
}

extern "C" void kernel_launch(void* const* d_in, const int* in_sizes, int n_in,
                              void* d_out, int out_size, void* d_ws, size_t ws_size,
                              hipStream_t stream) {
  const float* X = (const float*)d_in[0];
  const float* Y = (const float*)d_in[1];
  float* out = (float*)d_out;

  char* wsb = (char*)d_ws;
  bf16_t* Xbf = (bf16_t*)wsb;
  bf16_t* Ybf = (bf16_t*)(wsb + (size_t)NROWS * DDIM * 2);
  float* x2 = (float*)(wsb + 2 * (size_t)NROWS * DDIM * 2);
  float* y2 = x2 + NROWS;
  float* rslab = y2 + NROWS;                    // [8][8192][2]  512 KB
  float* cslab = rslab + SLICES * NROWS * 2;    // [64][8192]    2 MB
  unsigned* ctrs = (unsigned*)(cslab + 64 * NROWS);
  // counters are inside d_ws: the per-iteration 0xAA poison fill re-arms them
  // to 0xAAAAAAAA before every timed run; barrier target is 0xAAAAAAAA + 512.
  unsigned* c0 = ctrs;        // cacheline-separated
  unsigned* c1 = ctrs + 64;

  void* args_unused = nullptr; (void)args_unused;
  fused_kernel<<<NBLOCKS, 256, 0, stream>>>(X, Y, Xbf, Ybf, x2, y2,
                                            rslab, cslab, c0, c1, out);
}

// Round 7
// 78.778 us; speedup vs baseline: 2.5444x; 2.5444x over previous
//
#include <hip/hip_runtime.h>
#include <math.h>

// X[8192,64], Y[8192,64] fp32.
// d2[i][j] = x2_i + y2_j - 2<x_i,y_j>;  out = mean_i sqrt(min_j d2) + mean_j sqrt(min_i d2)
//
// R12 = R7 revert resubmit (R11 bench was an infra failure: container died).
// Best verified: 78.9 us. Fusion attempts all regressed:
// R8 cooperative launch never executed under harness graph capture; R9
// prep-fold into mine cost +9 us (VGPR/codegen regression in the hot loop);
// R10 hand-rolled spin barriers cost ~70 us/barrier (per-wave threadfence ->
// L2 writeback + 512 agent-scope pollers on one line; MfmaUtil 2.1% proved
// the compute is ~6-9 us). Floor decomposition: fill 41 us (harness-fixed,
// 82% HBM) + ~28 us dispatch/replay overhead (3 removal mechanisms failed)
// + ~10 us kernel work.
//
// 3 kernels. prep: fp32->bf16 (X pre-scaled by -2: exact in bf16) + row
// squares. mine: 512 blocks (64 itiles x 8 slices) = 2 blocks/CU, single
// occupancy round. A register-persistent, B LDS double-buffered (one barrier
// per chunk, reg prefetch during compute), 16x16x32 bf16 MFMA with C init =
// x2_i + y2_j -> accumulator exits as d2 directly; epilogue is pure
// v_min3_f32. Row-half col partials combined via 2KB LDS at the existing
// barrier -> cslab [64][8192]. finish: sqrt only (slabs carry full d2).
// Harness d_ws 0xAA fill (~41us, 268MB) is inside the timed window and is a
// fixed floor we cannot affect.

#define NROWS 8192
#define DDIM  64
#define ITILES 64     // 8192 / 128 i-rows per block
#define SLICES 8      // j: 8 slices x 1024
#define CHUNKS 8      // 8 x 128 j per block
#define LSTR 72       // LDS row stride (bf16): 144 B -> 16B-aligned, 2-way-max banks

typedef __bf16 bf16_t;
typedef bf16_t bf16x8 __attribute__((ext_vector_type(8)));
typedef float  f32x4  __attribute__((ext_vector_type(4)));

__global__ void prep_kernel(const float* __restrict__ X,
                            const float* __restrict__ Y,
                            bf16_t* __restrict__ Xbf, bf16_t* __restrict__ Ybf,
                            float* __restrict__ x2, float* __restrict__ y2,
                            float* __restrict__ out) {
  int t = blockIdx.x * blockDim.x + threadIdx.x;   // 0..65535
  int half = t >> 15;                              // 0: X, 1: Y
  int r = (t >> 2) & (NROWS - 1);
  int part = t & 3;                                // 16 elems per thread
  const float* src = half ? Y : X;
  bf16_t* dst = half ? Ybf : Xbf;
  float* sq = half ? y2 : x2;
  // X rows are pre-scaled by -2 so the MFMA computes -2<x,y> directly.
  // Scaling by 2 is an exponent shift: bf16(-2x) == -2*bf16(x) exactly.
  const float scale = half ? 1.0f : -2.0f;

  const float4* p = (const float4*)(src + r * DDIM + part * 16);
  float4 v0 = p[0], v1 = p[1], v2 = p[2], v3 = p[3];
  float s = 0.f;
  s = fmaf(v0.x, v0.x, s); s = fmaf(v0.y, v0.y, s);
  s = fmaf(v0.z, v0.z, s); s = fmaf(v0.w, v0.w, s);
  s = fmaf(v1.x, v1.x, s); s = fmaf(v1.y, v1.y, s);
  s = fmaf(v1.z, v1.z, s); s = fmaf(v1.w, v1.w, s);
  s = fmaf(v2.x, v2.x, s); s = fmaf(v2.y, v2.y, s);
  s = fmaf(v2.z, v2.z, s); s = fmaf(v2.w, v2.w, s);
  s = fmaf(v3.x, v3.x, s); s = fmaf(v3.y, v3.y, s);
  s = fmaf(v3.z, v3.z, s); s = fmaf(v3.w, v3.w, s);

  bf16x8 h0 = {(bf16_t)(scale * v0.x), (bf16_t)(scale * v0.y),
               (bf16_t)(scale * v0.z), (bf16_t)(scale * v0.w),
               (bf16_t)(scale * v1.x), (bf16_t)(scale * v1.y),
               (bf16_t)(scale * v1.z), (bf16_t)(scale * v1.w)};
  bf16x8 h1 = {(bf16_t)(scale * v2.x), (bf16_t)(scale * v2.y),
               (bf16_t)(scale * v2.z), (bf16_t)(scale * v2.w),
               (bf16_t)(scale * v3.x), (bf16_t)(scale * v3.y),
               (bf16_t)(scale * v3.z), (bf16_t)(scale * v3.w)};
  *(bf16x8*)&dst[r * DDIM + part * 16] = h0;
  *(bf16x8*)&dst[r * DDIM + part * 16 + 8] = h1;

  s += __shfl_xor(s, 1, 64);
  s += __shfl_xor(s, 2, 64);
  if (part == 0) sq[r] = s;
  if (t == 0) out[0] = 0.f;
}

__global__ __launch_bounds__(256, 2)
void mine_kernel(const bf16_t* __restrict__ Xbf, const bf16_t* __restrict__ Ybf,
                 const float* __restrict__ x2g, const float* __restrict__ y2g,
                 float* __restrict__ rslab, float* __restrict__ cslab) {
  __shared__ bf16_t Ys[2][128 * LSTR];   // 2 x 18 KB
  __shared__ float credL[2][2][128];     // [parity][rh][col] col-partial exchange

  const int tid = threadIdx.x;
  const int L = tid & 63;
  const int w = tid >> 6;
  const int lr = L & 15;
  const int q = L >> 4;
  const int rh = w >> 1;              // wave row-half
  const int ch = w & 1;               // wave col-half
  const int itile = blockIdx.x & (ITILES - 1);
  const int slice = blockIdx.x >> 6;  // 0..7
  const int i0 = itile * 128;
  const int rgb = rh * 64;
  const int cgb = ch * 64;
  const int jbase = slice * (CHUNKS * 128);   // slice * 1024

  // ---- A fragments: register-persistent (Xbf holds -2*X) ----
  bf16x8 Af[8];
#pragma unroll
  for (int a = 0; a < 4; ++a) {
    int row = i0 + rgb + a * 16 + lr;
#pragma unroll
    for (int h = 0; h < 2; ++h)
      Af[a * 2 + h] = *(const bf16x8*)&Xbf[row * DDIM + h * 32 + q * 8];
  }
  float x2r[16];
#pragma unroll
  for (int a = 0; a < 4; ++a) {
    float4 v = *(const float4*)&x2g[i0 + rgb + a * 16 + q * 4];
    x2r[a * 4 + 0] = v.x; x2r[a * 4 + 1] = v.y;
    x2r[a * 4 + 2] = v.z; x2r[a * 4 + 3] = v.w;
  }

  float rmin[16];
#pragma unroll
  for (int k = 0; k < 16; ++k) rmin[k] = INFINITY;

  // ---- prologue: stage chunk 0 ----
  bf16x8 Bst[4];
#pragma unroll
  for (int p = 0; p < 4; ++p) {
    int f = p * 256 + tid;
    Bst[p] = *(const bf16x8*)&Ybf[(jbase + (f >> 3)) * DDIM + (f & 7) * 8];
  }
#pragma unroll
  for (int p = 0; p < 4; ++p) {
    int f = p * 256 + tid;
    *(bf16x8*)&Ys[0][(f >> 3) * LSTR + (f & 7) * 8] = Bst[p];
  }
  __syncthreads();

  for (int cc = 0; cc < CHUNKS; ++cc) {
    const bf16_t* Yb = Ys[cc & 1];

    // y2 for this chunk (L2-hot, issued early so latency hides under staging)
    float y2c[4];
#pragma unroll
    for (int b = 0; b < 4; ++b)
      y2c[b] = y2g[jbase + cc * 128 + cgb + b * 16 + lr];

    // issue next chunk's global loads now; latency hidden by compute
    if (cc + 1 < CHUNKS) {
      int j0n = jbase + (cc + 1) * 128;
#pragma unroll
      for (int p = 0; p < 4; ++p) {
        int f = p * 256 + tid;
        Bst[p] = *(const bf16x8*)&Ybf[(j0n + (f >> 3)) * DDIM + (f & 7) * 8];
      }
    }

    // C init = x2_i + y2_j  (accumulator exits the MFMA pair as
    // d2 = x2 + y2 - 2<x,y> since A is pre-scaled by -2).
    // C/D layout: col = lr within 16, row = q*4+p.
    f32x4 acc[4][4];
#pragma unroll
    for (int a = 0; a < 4; ++a)
#pragma unroll
      for (int b = 0; b < 4; ++b) {
        acc[a][b][0] = x2r[a * 4 + 0] + y2c[b];
        acc[a][b][1] = x2r[a * 4 + 1] + y2c[b];
        acc[a][b][2] = x2r[a * 4 + 2] + y2c[b];
        acc[a][b][3] = x2r[a * 4 + 3] + y2c[b];
      }

#pragma unroll
    for (int b = 0; b < 4; ++b) {
      bf16x8 B0 = *(const bf16x8*)&Yb[(cgb + b * 16 + lr) * LSTR + q * 8];
      bf16x8 B1 = *(const bf16x8*)&Yb[(cgb + b * 16 + lr) * LSTR + 32 + q * 8];
#pragma unroll
      for (int a = 0; a < 4; ++a) {
        acc[a][b] = __builtin_amdgcn_mfma_f32_16x16x32_bf16(Af[a * 2 + 0], B0, acc[a][b], 0, 0, 0);
        acc[a][b] = __builtin_amdgcn_mfma_f32_16x16x32_bf16(Af[a * 2 + 1], B1, acc[a][b], 0, 0, 0);
      }
    }

    // ---- epilogue: acc IS d2; pure min3 trees ----
    float cmin[4] = {INFINITY, INFINITY, INFINITY, INFINITY};
#pragma unroll
    for (int a = 0; a < 4; ++a) {
#pragma unroll
      for (int p = 0; p < 4; ++p) {
        float rm = rmin[a * 4 + p];
        rm = fminf(fminf(rm, acc[a][0][p]), acc[a][1][p]);
        rmin[a * 4 + p] = fminf(fminf(rm, acc[a][2][p]), acc[a][3][p]);
      }
#pragma unroll
      for (int b = 0; b < 4; ++b) {
        float cm = cmin[b];
        cm = fminf(fminf(cm, acc[a][b][0]), acc[a][b][1]);
        cmin[b] = fminf(fminf(cm, acc[a][b][2]), acc[a][b][3]);
      }
    }
#pragma unroll
    for (int b = 0; b < 4; ++b) {
      cmin[b] = fminf(cmin[b], __shfl_xor(cmin[b], 16, 64));
      cmin[b] = fminf(cmin[b], __shfl_xor(cmin[b], 32, 64));
    }
    float v = cmin[0];
    if (q == 1) v = cmin[1];
    else if (q == 2) v = cmin[2];
    else if (q == 3) v = cmin[3];
    credL[cc & 1][rh][cgb + L] = v;   // col partial (full d2) for this row-half

    // ---- write prefetched chunk into the other buffer, single barrier ----
    if (cc + 1 < CHUNKS) {
      bf16_t* Yn = Ys[(cc + 1) & 1];
#pragma unroll
      for (int p = 0; p < 4; ++p) {
        int f = p * 256 + tid;
        *(bf16x8*)&Yn[(f >> 3) * LSTR + (f & 7) * 8] = Bst[p];
      }
    }
    __syncthreads();

    // combine the two row-halves' col partials; each cslab slot written once.
    // credL[cc&1] is not rewritten until chunk cc+2's epilogue, which is
    // separated from this read by the barrier at the end of chunk cc+1.
    if (tid < 128) {
      float m = fminf(credL[cc & 1][0][tid], credL[cc & 1][1][tid]);
      cslab[itile * NROWS + jbase + cc * 128 + tid] = m;
    }
  }

  // ---- row mins (full d2): reduce across 16 col-lanes, [slice][row][ch] ----
#pragma unroll
  for (int a = 0; a < 4; ++a)
#pragma unroll
    for (int p = 0; p < 4; ++p) {
      float v = rmin[a * 4 + p];
      v = fminf(v, __shfl_xor(v, 1, 64));
      v = fminf(v, __shfl_xor(v, 2, 64));
      v = fminf(v, __shfl_xor(v, 4, 64));
      v = fminf(v, __shfl_xor(v, 8, 64));
      if (lr == 0)
        rslab[slice * (NROWS * 2) + (i0 + rgb + a * 16 + q * 4 + p) * 2 + ch] = v;
    }
}

// blocks [0,32): rows (256 rows each). blocks [32,160): cols (64 cols each,
// 4 thread-segments x 16 partials, LDS combine). Slabs carry full d2.
__global__ void finish_kernel(const float* __restrict__ rslab,
                              const float* __restrict__ cslab,
                              float* __restrict__ out) {
  const int b = blockIdx.x;
  const int tid = threadIdx.x;
  if (b < 32) {
    int row = b * 256 + tid;
    float m = INFINITY;
#pragma unroll
    for (int g = 0; g < SLICES; ++g) {
      float2 v = *(const float2*)&rslab[g * (NROWS * 2) + row * 2];
      m = fminf(m, fminf(v.x, v.y));
    }
    float v = sqrtf(fmaxf(m, 0.f)) * (1.0f / 8192.0f);
#pragma unroll
    for (int off = 32; off > 0; off >>= 1) v += __shfl_down(v, off, 64);
    __shared__ float partial[4];
    if ((tid & 63) == 0) partial[tid >> 6] = v;
    __syncthreads();
    if (tid == 0)
      atomicAdd(out, partial[0] + partial[1] + partial[2] + partial[3]);
  } else {
    int j = (b - 32) * 64 + (tid & 63);
    int seg = tid >> 6;
    float m = INFINITY;
#pragma unroll
    for (int k = 0; k < 16; ++k)
      m = fminf(m, cslab[(seg * 16 + k) * NROWS + j]);
    __shared__ float red[4][64];
    red[seg][tid & 63] = m;
    __syncthreads();
    if (tid < 64) {
      float mc = fminf(fminf(red[0][tid], red[1][tid]),
                       fminf(red[2][tid], red[3][tid]));
      float v = sqrtf(fmaxf(mc, 0.f)) * (1.0f / 8192.0f);
#pragma unroll
      for (int off = 32; off > 0; off >>= 1) v += __shfl_down(v, off, 64);
      if (tid == 0) atomicAdd(out, v);
    }
  }
}

extern "C" void kernel_launch(void* const* d_in, const int* in_sizes, int n_in,
                              void* d_out, int out_size, void* d_ws, size_t ws_size,
                              hipStream_t stream) {
  const float* X = (const float*)d_in[0];
  const float* Y = (const float*)d_in[1];
  float* out = (float*)d_out;

  char* wsb = (char*)d_ws;
  bf16_t* Xbf = (bf16_t*)wsb;
  bf16_t* Ybf = (bf16_t*)(wsb + (size_t)NROWS * DDIM * 2);
  float* x2 = (float*)(wsb + 2 * (size_t)NROWS * DDIM * 2);
  float* y2 = x2 + NROWS;
  float* rslab = y2 + NROWS;                    // [8][8192][2]  512 KB
  float* cslab = rslab + SLICES * NROWS * 2;    // [64][8192]    2 MB

  prep_kernel<<<(2 * NROWS * 4) / 256, 256, 0, stream>>>(X, Y, Xbf, Ybf, x2, y2, out);
  mine_kernel<<<ITILES * SLICES, 256, 0, stream>>>(Xbf, Ybf, x2, y2, rslab, cslab);
  finish_kernel<<<160, 256, 0, stream>>>(rslab, cslab, out);
}